// Round 3
// baseline (78.256 us; speedup 1.0000x reference)
//
#include <hip/hip_runtime.h>

// Problem constants (fixed by reference setup_inputs)
#define NB 4
#define NC 64
#define NH 256
#define NW 256
#define HW (NH * NW)            // 65536 floats per (b,c) plane

__device__ __forceinline__ float4 f4zero() { return make_float4(0.f, 0.f, 0.f, 0.f); }

// Kernel 1: per-pixel reciprocal L2 norms over channels for image and event.
// One thread = 4 consecutive w (float4). 65536 threads total.
__global__ __launch_bounds__(256) void k_norms(
    const float4* __restrict__ img, const float4* __restrict__ ev,
    float4* __restrict__ rni, float4* __restrict__ rne)
{
    int t = blockIdx.x * 256 + threadIdx.x;       // 0..65535
    int b = t >> 14;                              // t / 16384  (HW/4 = 16384)
    int hw4 = t & 16383;
    const float4* ip = img + (size_t)b * NC * (HW / 4) + hw4;
    const float4* ep = ev  + (size_t)b * NC * (HW / 4) + hw4;

    float sx = 0.f, sy = 0.f, sz = 0.f, sw = 0.f;
    float tx = 0.f, ty = 0.f, tz = 0.f, tw = 0.f;
#pragma unroll 4
    for (int c = 0; c < NC; ++c) {
        float4 iv = ip[(size_t)c * (HW / 4)];
        float4 evv = ep[(size_t)c * (HW / 4)];
        sx = fmaf(iv.x, iv.x, sx);
        sy = fmaf(iv.y, iv.y, sy);
        sz = fmaf(iv.z, iv.z, sz);
        sw = fmaf(iv.w, iv.w, sw);
        tx = fmaf(evv.x, evv.x, tx);
        ty = fmaf(evv.y, evv.y, ty);
        tz = fmaf(evv.z, evv.z, tz);
        tw = fmaf(evv.w, evv.w, tw);
    }
    float4 oi, oe;
    oi.x = 1.f / fmaxf(sqrtf(sx), 1e-12f);
    oi.y = 1.f / fmaxf(sqrtf(sy), 1e-12f);
    oi.z = 1.f / fmaxf(sqrtf(sz), 1e-12f);
    oi.w = 1.f / fmaxf(sqrtf(sw), 1e-12f);
    oe.x = 1.f / fmaxf(sqrtf(tx), 1e-12f);
    oe.y = 1.f / fmaxf(sqrtf(ty), 1e-12f);
    oe.z = 1.f / fmaxf(sqrtf(tz), 1e-12f);
    oe.w = 1.f / fmaxf(sqrtf(tw), 1e-12f);
    rni[t] = oi;
    rne[t] = oe;
}

// Kernel 2: affinity. One wave (64 lanes) = one full image row; each lane owns
// 4 consecutive w. Neighbor w +/- 1 via wave shuffles. 8 offsets accumulated in
// registers over the channel loop; normalization scales applied in epilogue.
__global__ __launch_bounds__(256) void k_aff(
    const float* __restrict__ img, const float* __restrict__ ev,
    const float* __restrict__ rni, const float* __restrict__ rne,
    float* __restrict__ out)
{
    int lane = threadIdx.x & 63;
    int ty   = threadIdx.x >> 6;                  // wave id within block = row
    int bh   = blockIdx.x * 4 + ty;               // 0..1023 (B*H rows)
    int b = bh >> 8;
    int h = bh & 255;
    int w = lane << 2;                            // 4 w per lane

    const size_t pbase = (size_t)b * NC * HW + (size_t)h * NW + w;
    const float* ibase = img + pbase;
    const float* ebase = ev + pbase;
    const bool hm = (h > 0);
    const bool hp = (h < NH - 1);

    float acc[8][4];
#pragma unroll
    for (int k = 0; k < 8; ++k)
#pragma unroll
        for (int x = 0; x < 4; ++x) acc[k][x] = 0.f;

#pragma unroll 2
    for (int c = 0; c < NC; ++c) {
        const float* p = ibase + (size_t)c * HW;
        float4 zm = hm ? *(const float4*)(p - NW) : f4zero();
        float4 zz = *(const float4*)(p);
        float4 zp = hp ? *(const float4*)(p + NW) : f4zero();
        float4 ee = *(const float4*)(ebase + (size_t)c * HW);

        float lm = __shfl_up(zm.w, 1);
        float lz = __shfl_up(zz.w, 1);
        float lp = __shfl_up(zp.w, 1);
        float rm = __shfl_down(zm.x, 1);
        float rz = __shfl_down(zz.x, 1);
        float rp = __shfl_down(zp.x, 1);
        if (lane == 0)  { lm = 0.f; lz = 0.f; lp = 0.f; }
        if (lane == 63) { rm = 0.f; rz = 0.f; rp = 0.f; }

        // 6-wide windows per row: indices 0..5 cover w-1 .. w+4
        float m6[6] = { lm, zm.x, zm.y, zm.z, zm.w, rm };
        float z6[6] = { lz, zz.x, zz.y, zz.z, zz.w, rz };
        float p6[6] = { lp, zp.x, zp.y, zp.z, zp.w, rp };
        float sqm[6], sqz[6], sqp[6];
#pragma unroll
        for (int i = 0; i < 6; ++i) {
            sqm[i] = m6[i] * m6[i];
            sqz[i] = z6[i] * z6[i];
            sqp[i] = p6[i] * p6[i];
        }
        float pe[4] = { z6[1] * ee.x, z6[2] * ee.y, z6[3] * ee.z, z6[4] * ee.w };

#pragma unroll
        for (int x = 0; x < 4; ++x) {
            acc[0][x] = fmaf(sqm[x],     pe[x], acc[0][x]);  // (-1,-1)
            acc[1][x] = fmaf(sqm[x + 1], pe[x], acc[1][x]);  // (-1, 0)
            acc[2][x] = fmaf(sqm[x + 2], pe[x], acc[2][x]);  // (-1,+1)
            acc[3][x] = fmaf(sqz[x],     pe[x], acc[3][x]);  // ( 0,-1)
            acc[4][x] = fmaf(sqz[x + 2], pe[x], acc[4][x]);  // ( 0,+1)
            acc[5][x] = fmaf(sqp[x],     pe[x], acc[5][x]);  // (+1,-1)
            acc[6][x] = fmaf(sqp[x + 1], pe[x], acc[6][x]);  // (+1, 0)
            acc[7][x] = fmaf(sqp[x + 2], pe[x], acc[7][x]);  // (+1,+1)
        }
    }

    // Epilogue: normalization scales.
    const size_t nbase = (size_t)b * HW + (size_t)h * NW + w;
    const float* rb = rni + nbase;
    float4 nm = hm ? *(const float4*)(rb - NW) : f4zero();
    float4 nz = *(const float4*)(rb);
    float4 np = hp ? *(const float4*)(rb + NW) : f4zero();
    float4 ne = *(const float4*)(rne + nbase);

    float lnm = __shfl_up(nm.w, 1);
    float lnz = __shfl_up(nz.w, 1);
    float lnp = __shfl_up(np.w, 1);
    float rnm = __shfl_down(nm.x, 1);
    float rnz = __shfl_down(nz.x, 1);
    float rnp = __shfl_down(np.x, 1);
    if (lane == 0)  { lnm = 0.f; lnz = 0.f; lnp = 0.f; }
    if (lane == 63) { rnm = 0.f; rnz = 0.f; rnp = 0.f; }

    float nm6[6] = { lnm, nm.x, nm.y, nm.z, nm.w, rnm };
    float nz6[6] = { lnz, nz.x, nz.y, nz.z, nz.w, rnz };
    float np6[6] = { lnp, np.x, np.y, np.z, np.w, rnp };
    float nev[4] = { ne.x, ne.y, ne.z, ne.w };

    float ctr[4];
#pragma unroll
    for (int x = 0; x < 4; ++x) ctr[x] = nz6[x + 1] * nev[x];

    // neighbor rn per offset k, per pixel x
    float* outp = out + (((size_t)b * 8) * NH + h) * NW + w;
#pragma unroll
    for (int k = 0; k < 8; ++k) {
        float nbv[4];
#pragma unroll
        for (int x = 0; x < 4; ++x) {
            float v;
            switch (k) {
                case 0: v = nm6[x];     break;
                case 1: v = nm6[x + 1]; break;
                case 2: v = nm6[x + 2]; break;
                case 3: v = nz6[x];     break;
                case 4: v = nz6[x + 2]; break;
                case 5: v = np6[x];     break;
                case 6: v = np6[x + 1]; break;
                default: v = np6[x + 2]; break;
            }
            nbv[x] = v;
        }
        float4 o;
        o.x = fmaxf(acc[k][0] * (nbv[0] * nbv[0]) * ctr[0], 0.f);
        o.y = fmaxf(acc[k][1] * (nbv[1] * nbv[1]) * ctr[1], 0.f);
        o.z = fmaxf(acc[k][2] * (nbv[2] * nbv[2]) * ctr[2], 0.f);
        o.w = fmaxf(acc[k][3] * (nbv[3] * nbv[3]) * ctr[3], 0.f);
        *(float4*)(outp + (size_t)k * NH * NW) = o;
    }
}

extern "C" void kernel_launch(void* const* d_in, const int* in_sizes, int n_in,
                              void* d_out, int out_size, void* d_ws, size_t ws_size,
                              hipStream_t stream) {
    (void)in_sizes; (void)n_in; (void)out_size; (void)ws_size;
    const float* img = (const float*)d_in[0];
    const float* ev  = (const float*)d_in[1];
    float* rni = (float*)d_ws;                 // B*H*W floats (1 MB)
    float* rne = rni + (size_t)NB * HW;        // B*H*W floats (1 MB)
    float* out = (float*)d_out;

    // 65536 threads: 256 blocks x 256 threads
    k_norms<<<256, 256, 0, stream>>>((const float4*)img, (const float4*)ev,
                                     (float4*)rni, (float4*)rne);
    // 1024 rows, 4 rows (waves) per block
    k_aff<<<256, 256, 0, stream>>>(img, ev, rni, rne, out);
}

// Round 4
// 30.449 us; speedup vs baseline: 2.5701x; 2.5701x over previous
//
#include <hip/hip_runtime.h>

// Problem constants (fixed by reference setup_inputs)
#define NB 4
#define NC 64
#define NH 256
#define NW 256
#define HW (NH * NW)            // 65536 floats per (b,c) plane
#define CPW 16                  // channels per wave (NC / 4 waves)

__device__ __forceinline__ float4 f4zero() { return make_float4(0.f, 0.f, 0.f, 0.f); }

// Fused kernel: one block = one image row (b,h). 4 waves; wave wv handles
// channels [wv*16, wv*16+16). Each lane owns 4 consecutive w (float4) of the
// full row; horizontal neighbors via wave shuffles. Each wave accumulates:
//   acc[8][4]  raw affinity dots  sum_c img_nb^2 * img_ctr * ev_ctr
//   si[3][4]   img^2 channel-sums for rows h-1, h, h+1 (own w positions)
//   se[4]      ev^2 channel-sums (center row)
// Partials tree-reduced through LDS; wave 0 applies reciprocal norms + relu.
__global__ __launch_bounds__(256) void k_fused(
    const float* __restrict__ img, const float* __restrict__ ev,
    float* __restrict__ out)
{
    __shared__ float red[2][48][64];   // two reduction slots, [value][lane]

    const int lane = threadIdx.x & 63;
    const int wv   = threadIdx.x >> 6;           // 0..3 = channel chunk

    // XCD-aware swizzle: 1024 blocks, 8 XCDs -> contiguous 128-row chunks per
    // XCD so h-adjacent rows (which share img rows) live on the same L2.
    const int bid = blockIdx.x;
    const int swz = (bid & 7) * 128 + (bid >> 3);   // bijective, 1024 % 8 == 0
    const int b = swz >> 8;
    const int h = swz & 255;
    const int w = lane << 2;

    const bool hm = (h > 0);
    const bool hp = (h < NH - 1);

    const size_t base = (size_t)b * NC * HW + (size_t)(wv * CPW) * HW
                      + (size_t)h * NW + w;
    const float* ibase = img + base;
    const float* ebase = ev + base;

    float acc[8][4];
    float si[3][4];
    float se[4];
#pragma unroll
    for (int k = 0; k < 8; ++k)
#pragma unroll
        for (int x = 0; x < 4; ++x) acc[k][x] = 0.f;
#pragma unroll
    for (int r = 0; r < 3; ++r)
#pragma unroll
        for (int x = 0; x < 4; ++x) si[r][x] = 0.f;
#pragma unroll
    for (int x = 0; x < 4; ++x) se[x] = 0.f;

#pragma unroll 2
    for (int c = 0; c < CPW; ++c) {
        const float* p = ibase + (size_t)c * HW;
        float4 zm = hm ? *(const float4*)(p - NW) : f4zero();
        float4 zz = *(const float4*)(p);
        float4 zp = hp ? *(const float4*)(p + NW) : f4zero();
        float4 ee = *(const float4*)(ebase + (size_t)c * HW);

        float lm = __shfl_up(zm.w, 1);
        float lz = __shfl_up(zz.w, 1);
        float lp = __shfl_up(zp.w, 1);
        float rm = __shfl_down(zm.x, 1);
        float rz = __shfl_down(zz.x, 1);
        float rp = __shfl_down(zp.x, 1);
        if (lane == 0)  { lm = 0.f; lz = 0.f; lp = 0.f; }
        if (lane == 63) { rm = 0.f; rz = 0.f; rp = 0.f; }

        // 6-wide windows: indices 0..5 cover w-1 .. w+4
        float m6[6] = { lm, zm.x, zm.y, zm.z, zm.w, rm };
        float z6[6] = { lz, zz.x, zz.y, zz.z, zz.w, rz };
        float p6[6] = { lp, zp.x, zp.y, zp.z, zp.w, rp };
        float sqm[6], sqz[6], sqp[6];
#pragma unroll
        for (int i = 0; i < 6; ++i) {
            sqm[i] = m6[i] * m6[i];
            sqz[i] = z6[i] * z6[i];
            sqp[i] = p6[i] * p6[i];
        }
        // norm-sum accumulation (reuse squares; own w positions = window 1..4)
#pragma unroll
        for (int x = 0; x < 4; ++x) {
            si[0][x] += sqm[x + 1];
            si[1][x] += sqz[x + 1];
            si[2][x] += sqp[x + 1];
        }
        se[0] = fmaf(ee.x, ee.x, se[0]);
        se[1] = fmaf(ee.y, ee.y, se[1]);
        se[2] = fmaf(ee.z, ee.z, se[2]);
        se[3] = fmaf(ee.w, ee.w, se[3]);

        float pe[4] = { z6[1] * ee.x, z6[2] * ee.y, z6[3] * ee.z, z6[4] * ee.w };
#pragma unroll
        for (int x = 0; x < 4; ++x) {
            acc[0][x] = fmaf(sqm[x],     pe[x], acc[0][x]);  // (-1,-1)
            acc[1][x] = fmaf(sqm[x + 1], pe[x], acc[1][x]);  // (-1, 0)
            acc[2][x] = fmaf(sqm[x + 2], pe[x], acc[2][x]);  // (-1,+1)
            acc[3][x] = fmaf(sqz[x],     pe[x], acc[3][x]);  // ( 0,-1)
            acc[4][x] = fmaf(sqz[x + 2], pe[x], acc[4][x]);  // ( 0,+1)
            acc[5][x] = fmaf(sqp[x],     pe[x], acc[5][x]);  // (+1,-1)
            acc[6][x] = fmaf(sqp[x + 1], pe[x], acc[6][x]);  // (+1, 0)
            acc[7][x] = fmaf(sqp[x + 2], pe[x], acc[7][x]);  // (+1,+1)
        }
    }

    // ---- cross-wave tree reduction through LDS (48 floats per lane) ----
    // value index v: 0..31 = acc[v>>2][v&3], 32..43 = si[(v-32)>>2][(v-32)&3],
    // 44..47 = se[v-44]. Layout [value][lane]: stride-1 across lanes.
    if (wv >= 2) {
        const int s = wv - 2;
#pragma unroll
        for (int k = 0; k < 8; ++k)
#pragma unroll
            for (int x = 0; x < 4; ++x) red[s][k * 4 + x][lane] = acc[k][x];
#pragma unroll
        for (int r = 0; r < 3; ++r)
#pragma unroll
            for (int x = 0; x < 4; ++x) red[s][32 + r * 4 + x][lane] = si[r][x];
#pragma unroll
        for (int x = 0; x < 4; ++x) red[s][44 + x][lane] = se[x];
    }
    __syncthreads();
    if (wv < 2) {
        const int s = wv;
#pragma unroll
        for (int k = 0; k < 8; ++k)
#pragma unroll
            for (int x = 0; x < 4; ++x) acc[k][x] += red[s][k * 4 + x][lane];
#pragma unroll
        for (int r = 0; r < 3; ++r)
#pragma unroll
            for (int x = 0; x < 4; ++x) si[r][x] += red[s][32 + r * 4 + x][lane];
#pragma unroll
        for (int x = 0; x < 4; ++x) se[x] += red[s][44 + x][lane];
    }
    __syncthreads();
    if (wv == 1) {
#pragma unroll
        for (int k = 0; k < 8; ++k)
#pragma unroll
            for (int x = 0; x < 4; ++x) red[0][k * 4 + x][lane] = acc[k][x];
#pragma unroll
        for (int r = 0; r < 3; ++r)
#pragma unroll
            for (int x = 0; x < 4; ++x) red[0][32 + r * 4 + x][lane] = si[r][x];
#pragma unroll
        for (int x = 0; x < 4; ++x) red[0][44 + x][lane] = se[x];
    }
    __syncthreads();
    if (wv != 0) return;

#pragma unroll
    for (int k = 0; k < 8; ++k)
#pragma unroll
        for (int x = 0; x < 4; ++x) acc[k][x] += red[0][k * 4 + x][lane];
#pragma unroll
    for (int r = 0; r < 3; ++r)
#pragma unroll
        for (int x = 0; x < 4; ++x) si[r][x] += red[0][32 + r * 4 + x][lane];
#pragma unroll
    for (int x = 0; x < 4; ++x) se[x] += red[0][44 + x][lane];

    // ---- epilogue (wave 0 only): reciprocal norms, windows, scale, relu ----
    float rnm[4], rnz[4], rnp[4], rne[4];
#pragma unroll
    for (int x = 0; x < 4; ++x) {
        rnm[x] = 1.f / fmaxf(sqrtf(si[0][x]), 1e-12f);
        rnz[x] = 1.f / fmaxf(sqrtf(si[1][x]), 1e-12f);
        rnp[x] = 1.f / fmaxf(sqrtf(si[2][x]), 1e-12f);
        rne[x] = 1.f / fmaxf(sqrtf(se[x]), 1e-12f);
    }

    float lnm = __shfl_up(rnm[3], 1);
    float lnz = __shfl_up(rnz[3], 1);
    float lnp = __shfl_up(rnp[3], 1);
    float rnm_ = __shfl_down(rnm[0], 1);
    float rnz_ = __shfl_down(rnz[0], 1);
    float rnp_ = __shfl_down(rnp[0], 1);
    if (lane == 0)  { lnm = 0.f; lnz = 0.f; lnp = 0.f; }
    if (lane == 63) { rnm_ = 0.f; rnz_ = 0.f; rnp_ = 0.f; }

    float nm6[6] = { lnm, rnm[0], rnm[1], rnm[2], rnm[3], rnm_ };
    float nz6[6] = { lnz, rnz[0], rnz[1], rnz[2], rnz[3], rnz_ };
    float np6[6] = { lnp, rnp[0], rnp[1], rnp[2], rnp[3], rnp_ };

    float ctr[4];
#pragma unroll
    for (int x = 0; x < 4; ++x) ctr[x] = nz6[x + 1] * rne[x];

    float* outp = out + (((size_t)b * 8) * NH + h) * NW + w;
#pragma unroll
    for (int k = 0; k < 8; ++k) {
        float nbv[4];
#pragma unroll
        for (int x = 0; x < 4; ++x) {
            float v;
            switch (k) {
                case 0: v = nm6[x];     break;
                case 1: v = nm6[x + 1]; break;
                case 2: v = nm6[x + 2]; break;
                case 3: v = nz6[x];     break;
                case 4: v = nz6[x + 2]; break;
                case 5: v = np6[x];     break;
                case 6: v = np6[x + 1]; break;
                default: v = np6[x + 2]; break;
            }
            nbv[x] = v;
        }
        float4 o;
        o.x = fmaxf(acc[k][0] * (nbv[0] * nbv[0]) * ctr[0], 0.f);
        o.y = fmaxf(acc[k][1] * (nbv[1] * nbv[1]) * ctr[1], 0.f);
        o.z = fmaxf(acc[k][2] * (nbv[2] * nbv[2]) * ctr[2], 0.f);
        o.w = fmaxf(acc[k][3] * (nbv[3] * nbv[3]) * ctr[3], 0.f);
        *(float4*)(outp + (size_t)k * NH * NW) = o;
    }
}

extern "C" void kernel_launch(void* const* d_in, const int* in_sizes, int n_in,
                              void* d_out, int out_size, void* d_ws, size_t ws_size,
                              hipStream_t stream) {
    (void)in_sizes; (void)n_in; (void)out_size; (void)d_ws; (void)ws_size;
    const float* img = (const float*)d_in[0];
    const float* ev  = (const float*)d_in[1];
    float* out = (float*)d_out;

    // 1024 blocks (one per row), 256 threads (4 waves x 16 channels)
    k_fused<<<NB * NH, 256, 0, stream>>>(img, ev, out);
}